// Round 7
// baseline (1100.441 us; speedup 1.0000x reference)
//
#include <hip/hip_runtime.h>
#include <hip/hip_bf16.h>
#include <cstdint>

typedef __bf16 bf16;
typedef bf16 bf16x4 __attribute__((ext_vector_type(4)));
typedef bf16 bf16x8 __attribute__((ext_vector_type(8)));
typedef _Float16 f16;
typedef f16 f16x4 __attribute__((ext_vector_type(4)));
typedef f16 f16x8 __attribute__((ext_vector_type(8)));
typedef float f32x4 __attribute__((ext_vector_type(4)));

#define MFMA16(a, b, c) __builtin_amdgcn_mfma_f32_16x16x32_bf16((a), (b), (c), 0, 0, 0)
#define MFMA16HF(a, b, c) __builtin_amdgcn_mfma_f32_16x16x32_f16((a), (b), (c), 0, 0, 0)

// 0.125 * log2(e): folded into Q at the QKV-GEMM epilogue
#define QSCALE 0.18033688011112042f

// async global->LDS DMA, 16B/lane. LDS dest must be wave-uniform base + lane*16.
__device__ inline void async16(const bf16* g, bf16* l) {
  __builtin_amdgcn_global_load_lds(
      (const __attribute__((address_space(1))) void*)g,
      (__attribute__((address_space(3))) void*)l, 16, 0, 0);
}

// ------------------------------------------------------------------
// fused cast fp32 -> bf16 for all four inputs (one launch)
// ------------------------------------------------------------------
__global__ void cast_all(const float* __restrict__ x, const float* __restrict__ wq,
                         const float* __restrict__ wkv, const float* __restrict__ wp,
                         bf16* __restrict__ xb, bf16* __restrict__ w1b,
                         bf16* __restrict__ wpb) {
  const int i = blockIdx.x * blockDim.x + threadIdx.x;
  const float4* src;
  bf16x4* dst;
  int idx;
  if (i < 2097152) {
    src = (const float4*)x; dst = (bf16x4*)xb; idx = i;
  } else if (i < 2359296) {
    src = (const float4*)wq; dst = (bf16x4*)w1b; idx = i - 2097152;
  } else if (i < 2490368) {
    src = (const float4*)wkv; dst = (bf16x4*)(w1b + 1048576); idx = i - 2359296;
  } else {
    src = (const float4*)wp; dst = (bf16x4*)wpb; idx = i - 2490368;
  }
  const float4 v = src[idx];
  bf16x4 o;
  o.x = (bf16)v.x; o.y = (bf16)v.y; o.z = (bf16)v.z; o.w = (bf16)v.w;
  dst[idx] = o;
}

// ------------------------------------------------------------------
// GEMM1: C[m,e] = sum_c x[m,c] * W1[e,c]   (M=8192, N=1536, K=1024)
// Q pre-scaled by QSCALE (bf16), K bf16 [b,kvh,t,d],
// V stored f16 TRANSPOSED: vT[b,kvh,d,t]  (for direct A-frag reads).
// ------------------------------------------------------------------
__global__ __launch_bounds__(256, 2)
void gemm_qkv(const bf16* __restrict__ A, const bf16* __restrict__ B,
              bf16* __restrict__ qb, bf16* __restrict__ kb, f16* __restrict__ vb) {
  constexpr int K = 1024;
  __shared__ bf16 sA[128 * 64];
  __shared__ bf16 sB[128 * 64];
  const int tid = threadIdx.x;
  const int lane = tid & 63, wid = tid >> 6;
  const int col = lane & 15, quad = lane >> 4;
  const int wm = wid >> 1, wn = wid & 1;
  const int m0 = blockIdx.y * 128, n0 = blockIdx.x * 128;
  const int c7 = col & 7;

  f32x4 acc[4][4];
  const f32x4 z = {0.f, 0.f, 0.f, 0.f};
#pragma unroll
  for (int mi = 0; mi < 4; mi++)
#pragma unroll
    for (int ni = 0; ni < 4; ni++) acc[mi][ni] = z;

  for (int k0 = 0; k0 < K; k0 += 64) {
    __syncthreads();
#pragma unroll
    for (int c = 0; c < 4; ++c) {
      const int idx = c * 256 + tid;
      const int row = idx >> 3, kc = idx & 7;
      const int gkc = kc ^ (row & 7);
      async16(&A[(size_t)(m0 + row) * K + k0 + gkc * 8], &sA[idx * 8]);
      async16(&B[(size_t)(n0 + row) * K + k0 + gkc * 8], &sB[idx * 8]);
    }
    __syncthreads();  // vmcnt(0) drain: DMA complete
#pragma unroll
    for (int ks = 0; ks < 2; ++ks) {
      bf16x8 af[4], bfr[4];
#pragma unroll
      for (int i = 0; i < 4; i++)
        af[i] = *(const bf16x8*)&sA[(wm * 64 + i * 16 + col) * 64 +
                                    (((ks * 4 + quad) ^ c7) << 3)];
#pragma unroll
      for (int i = 0; i < 4; i++)
        bfr[i] = *(const bf16x8*)&sB[(wn * 64 + i * 16 + col) * 64 +
                                     (((ks * 4 + quad) ^ c7) << 3)];
#pragma unroll
      for (int mi = 0; mi < 4; mi++)
#pragma unroll
        for (int ni = 0; ni < 4; ni++)
          acc[mi][ni] = MFMA16(af[mi], bfr[ni], acc[mi][ni]);
    }
  }
#pragma unroll
  for (int mi = 0; mi < 4; mi++) {
#pragma unroll
    for (int ni = 0; ni < 4; ni++) {
      const int e = n0 + wn * 64 + ni * 16 + col;
      const int mB = m0 + wm * 64 + mi * 16 + quad * 4;  // first of 4 rows
      if (e < 1024) {
#pragma unroll
        for (int r = 0; r < 4; r++) {
          const int m = mB + r;
          const int bb = m >> 11, t = m & 2047;
          qb[(((size_t)bb * 16 + (e >> 6)) * 2048 + t) * 64 + (e & 63)] =
              (bf16)(acc[mi][ni][r] * QSCALE);
        }
      } else if (e < 1280) {
        const int f = e - 1024;
#pragma unroll
        for (int r = 0; r < 4; r++) {
          const int m = mB + r;
          const int bb = m >> 11, t = m & 2047;
          kb[(((size_t)bb * 4 + (f >> 6)) * 2048 + t) * 64 + (f & 63)] =
              (bf16)acc[mi][ni][r];
        }
      } else {
        const int f = e - 1280;
        const int bb = mB >> 11, t = mB & 2047;  // 4 rows same batch (t%4==0)
        f16x4 w;
#pragma unroll
        for (int r = 0; r < 4; r++) w[r] = (f16)acc[mi][ni][r];
        *(f16x4*)&vb[(((size_t)bb * 4 + (f >> 6)) * 64 + (f & 63)) * 2048 + t] = w;
      }
    }
  }
}

// ------------------------------------------------------------------
// GEMM2: out[m,e] = sum_c AO[m,c] * Wproj[e,c] + bias[e]  (fp32 out)
// ------------------------------------------------------------------
__global__ __launch_bounds__(256, 2)
void gemm_proj(const bf16* __restrict__ A, const bf16* __restrict__ B,
               const float* __restrict__ bias, float* __restrict__ out) {
  constexpr int K = 1024;
  __shared__ bf16 sA[128 * 64];
  __shared__ bf16 sB[128 * 64];
  const int tid = threadIdx.x;
  const int lane = tid & 63, wid = tid >> 6;
  const int col = lane & 15, quad = lane >> 4;
  const int wm = wid >> 1, wn = wid & 1;
  const int m0 = blockIdx.y * 128, n0 = blockIdx.x * 128;
  const int c7 = col & 7;

  f32x4 acc[4][4];
  const f32x4 z = {0.f, 0.f, 0.f, 0.f};
#pragma unroll
  for (int mi = 0; mi < 4; mi++)
#pragma unroll
    for (int ni = 0; ni < 4; ni++) acc[mi][ni] = z;

  for (int k0 = 0; k0 < K; k0 += 64) {
    __syncthreads();
#pragma unroll
    for (int c = 0; c < 4; ++c) {
      const int idx = c * 256 + tid;
      const int row = idx >> 3, kc = idx & 7;
      const int gkc = kc ^ (row & 7);
      async16(&A[(size_t)(m0 + row) * K + k0 + gkc * 8], &sA[idx * 8]);
      async16(&B[(size_t)(n0 + row) * K + k0 + gkc * 8], &sB[idx * 8]);
    }
    __syncthreads();
#pragma unroll
    for (int ks = 0; ks < 2; ++ks) {
      bf16x8 af[4], bfr[4];
#pragma unroll
      for (int i = 0; i < 4; i++)
        af[i] = *(const bf16x8*)&sA[(wm * 64 + i * 16 + col) * 64 +
                                    (((ks * 4 + quad) ^ c7) << 3)];
#pragma unroll
      for (int i = 0; i < 4; i++)
        bfr[i] = *(const bf16x8*)&sB[(wn * 64 + i * 16 + col) * 64 +
                                     (((ks * 4 + quad) ^ c7) << 3)];
#pragma unroll
      for (int mi = 0; mi < 4; mi++)
#pragma unroll
        for (int ni = 0; ni < 4; ni++)
          acc[mi][ni] = MFMA16(af[mi], bfr[ni], acc[mi][ni]);
    }
  }
#pragma unroll
  for (int mi = 0; mi < 4; mi++) {
#pragma unroll
    for (int ni = 0; ni < 4; ni++) {
      const int e = n0 + wn * 64 + ni * 16 + col;
      const float be = bias[e];
#pragma unroll
      for (int r = 0; r < 4; r++) {
        const int m = m0 + wm * 64 + mi * 16 + quad * 4 + r;
        out[(size_t)m * 1024 + e] = acc[mi][ni][r] + be;
      }
    }
  }
}

// ------------------------------------------------------------------
// Flash attention v4: KV-split across the block's 4 waves.
// Block = one 64-row q tile; wave w handles kv [w*512, w*512+512).
// Fixed-max softmax => partials (O_unnorm, l) combine by plain sum.
//  - K A-frags and V^T A-frags loaded DIRECT from global (no staging,
//    no barriers in the whole main loop).
//  - P goes S-regs -> wave-private swizzled sPt -> x32 f16 B-frags.
//  - Rowsums l via all-ones A-operand x32 MFMA.
//  - One __syncthreads total: before the cross-wave combine (through
//    the dead sPt space, f16).
// ------------------------------------------------------------------
__global__ __launch_bounds__(256, 4)
void attn_alibi(const bf16* __restrict__ qb, const bf16* __restrict__ kbp,
                const f16* __restrict__ vbp, bf16* __restrict__ ob) {
  __shared__ f16 sPt[4][64 * 64];  // per wave: P round-trip, then O^T partial
  __shared__ float sL[4][64];      // per wave: l partial per q
  const int tid = threadIdx.x;
  const int lane = tid & 63, wid = tid >> 6;
  const int col = lane & 15, quad = lane >> 4;
  const int ce = col & 14;  // pair-preserving xor swizzle key
  const int bh = blockIdx.y;
  const int b = bh >> 4, h = bh & 15, kvh = h & 3;
  const int qbase = blockIdx.x * 64;
  const int kvb = wid * 512;

  const bf16* qptr = qb + ((size_t)(b * 16 + h) * 2048 + qbase) * 64;
  const bf16* kptr = kbp + ((size_t)(b * 4 + kvh) * 2048) * 64;
  const f16* vTptr = vbp + ((size_t)(b * 4 + kvh) * 64) * 2048;

  // Q resident as B-operand frags (x32): B[n=q(col)][k=d=ks*32+quad*8+j]
  bf16x8 bq[4][2];
#pragma unroll
  for (int ni = 0; ni < 4; ni++)
#pragma unroll
    for (int ks = 0; ks < 2; ks++)
      bq[ni][ks] = *(const bf16x8*)&qptr[(ni * 16 + col) * 64 + ks * 32 + quad * 8];

  f16x8 ones;
#pragma unroll
  for (int j = 0; j < 8; j++) ones[j] = (f16)1.0f;

  f32x4 OT[4][4];  // O^T[d-tile nd][q-tile ni]; lane: d=nd*16+quad*4+r, q=ni*16+col
  f32x4 lC[4];
  const f32x4 z = {0.f, 0.f, 0.f, 0.f};
#pragma unroll
  for (int nd = 0; nd < 4; nd++) {
    lC[nd] = z;
#pragma unroll
    for (int ni = 0; ni < 4; ni++) OT[nd][ni] = z;
  }

  const float cb = exp2f(-0.5f * (float)(h + 1)) * QSCALE;  // bias slope, exp2 dom
  const int qoff = quad * 4 - col;
  f16* sp = sPt[wid];

  // K A-frag prefetch for first chunk
  bf16x8 ak[4][2];
#pragma unroll
  for (int mi = 0; mi < 4; mi++)
#pragma unroll
    for (int ks = 0; ks < 2; ks++)
      ak[mi][ks] = *(const bf16x8*)&kptr[(size_t)(kvb + mi * 16 + col) * 64 +
                                         ks * 32 + quad * 8];

  for (int cc = 0; cc < 8; ++cc) {
    const int c0 = kvb + cc * 64;
    const int cn = kvb + ((cc + 1) & 7) * 64;  // dummy wrap on last iter
    // prefetch next chunk's K frags
    bf16x8 akn[4][2];
#pragma unroll
    for (int mi = 0; mi < 4; mi++)
#pragma unroll
      for (int ks = 0; ks < 2; ks++)
        akn[mi][ks] = *(const bf16x8*)&kptr[(size_t)(cn + mi * 16 + col) * 64 +
                                            ks * 32 + quad * 8];

    // S^T = K Q^T (exp2 domain): lane holds kv=kb*16+quad*4+r, q=ni*16+col
    f32x4 S[4][4];
#pragma unroll
    for (int kb = 0; kb < 4; kb++)
#pragma unroll
      for (int ni = 0; ni < 4; ni++) S[kb][ni] = z;
#pragma unroll
    for (int ks = 0; ks < 2; ks++)
#pragma unroll
      for (int kb = 0; kb < 4; kb++)
#pragma unroll
        for (int ni = 0; ni < 4; ni++)
          S[kb][ni] = MFMA16(ak[kb][ks], bq[ni][ks], S[kb][ni]);

    // per 32-kv half: exp two 16-kv blocks -> sPt, then PV x32
#pragma unroll
    for (int ks = 0; ks < 2; ks++) {
#pragma unroll
      for (int kh = 0; kh < 2; kh++) {
        const int kb = ks * 2 + kh;
#pragma unroll
        for (int ni = 0; ni < 4; ni++) {
          const int U = c0 + kb * 16 - qbase - ni * 16;  // wave-uniform
          f32x4 p;
          if (U <= -15) {
            const float bb = cb * (float)(U + qoff);
#pragma unroll
            for (int r = 0; r < 4; r++)
              p[r] = __builtin_amdgcn_exp2f(S[kb][ni][r] + (bb + cb * (float)r));
          } else if (U >= 16) {
#pragma unroll
            for (int r = 0; r < 4; r++)
              p[r] = __builtin_amdgcn_exp2f(S[kb][ni][r]);
          } else {
            const float relf = (float)(U + qoff);
#pragma unroll
            for (int r = 0; r < 4; r++) {
              const float rr = relf + (float)r;
              const float bb = (rr <= 0.f) ? cb * rr : 0.f;
              p[r] = __builtin_amdgcn_exp2f(S[kb][ni][r] + bb);
            }
          }
          f16x4 w;
#pragma unroll
          for (int r = 0; r < 4; r++) w[r] = (f16)p[r];
          // unit u = kb*4+quad, swizzled by q&15 (pair-preserving)
          *(f16x4*)&sp[(ni * 16 + col) * 64 + (((kb * 4 + quad) ^ ce) << 2)] = w;
        }
      }
      // V^T A-frags direct from global: A[m=d=nd*16+col][k=kv=c0+ks*32+quad*8+j]
      f16x8 av[4];
#pragma unroll
      for (int nd = 0; nd < 4; nd++)
        av[nd] = *(const f16x8*)&vTptr[(size_t)(nd * 16 + col) * 2048 + c0 +
                                       ks * 32 + quad * 8];
      // P^T B-frags from sPt: B[k=kv=ks*32+quad*8+j][n=q=ni*16+col]
      f16x8 pB[4];
#pragma unroll
      for (int ni = 0; ni < 4; ni++)
        pB[ni] = *(const f16x8*)&sp[(ni * 16 + col) * 64 +
                                    (((ks * 8 + 2 * quad) ^ ce) << 2)];
#pragma unroll
      for (int ni = 0; ni < 4; ni++) {
#pragma unroll
        for (int nd = 0; nd < 4; nd++)
          OT[nd][ni] = MFMA16HF(av[nd], pB[ni], OT[nd][ni]);
        lC[ni] = MFMA16HF(ones, pB[ni], lC[ni]);
      }
    }
    // rotate K prefetch
#pragma unroll
    for (int mi = 0; mi < 4; mi++)
#pragma unroll
      for (int ks = 0; ks < 2; ks++) ak[mi][ks] = akn[mi][ks];
  }

  // write this wave's partials into its sPt region ([q][d] f16, swizzled) + l
#pragma unroll
  for (int ni = 0; ni < 4; ni++) {
#pragma unroll
    for (int nd = 0; nd < 4; nd++) {
      f16x4 w;
#pragma unroll
      for (int r = 0; r < 4; r++) w[r] = (f16)OT[nd][ni][r];
      *(f16x4*)&sp[(ni * 16 + col) * 64 + (((nd * 4 + quad) ^ ce) << 2)] = w;
    }
    if (quad == 0) sL[wid][ni * 16 + col] = lC[ni][0];
  }
  __syncthreads();

  // combine: wave w handles q rows [w*16, w*16+16); lane: q=w*16+col, d=quad*16+..
  {
    const int q = wid * 16 + col;
    const float lsum = sL[0][q] + sL[1][q] + sL[2][q] + sL[3][q];
    const float inv = 1.0f / lsum;
    const size_t rowb = ((size_t)b * 2048 + qbase + q) * 1024 + h * 64;
#pragma unroll
    for (int dh = 0; dh < 2; dh++) {
      // units u = quad*4 + dh*2 + {0,1} (pair-aligned), d = 16*quad+8*dh+0..7
      const int uoff = ((quad * 4 + dh * 2) ^ ce) << 2;
      float acc[8];
#pragma unroll
      for (int j = 0; j < 8; j++) acc[j] = 0.f;
#pragma unroll
      for (int w2 = 0; w2 < 4; w2++) {
        const f16x8 v = *(const f16x8*)&sPt[w2][q * 64 + uoff];
#pragma unroll
        for (int j = 0; j < 8; j++) acc[j] += (float)v[j];
      }
      bf16x8 o;
#pragma unroll
      for (int j = 0; j < 8; j++) o[j] = (bf16)(acc[j] * inv);
      *(bf16x8*)&ob[rowb + quad * 16 + dh * 8] = o;
    }
  }
}

// ------------------------------------------------------------------
extern "C" void kernel_launch(void* const* d_in, const int* in_sizes, int n_in,
                              void* d_out, int out_size, void* d_ws, size_t ws_size,
                              hipStream_t stream) {
  const float* x     = (const float*)d_in[0];
  const float* Wq    = (const float*)d_in[1];
  const float* Wkv   = (const float*)d_in[2];
  const float* Wproj = (const float*)d_in[3];
  const float* bproj = (const float*)d_in[4];
  float* out = (float*)d_out;

  bf16* xb  = (bf16*)d_ws;            // 8192*1024
  bf16* w1b = xb  + 8388608;          // 1536*1024
  bf16* wpb = w1b + 1572864;          // 1024*1024
  bf16* qb  = wpb + 1048576;          // [4,16,2048,64]
  bf16* kb  = qb  + 8388608;          // [4,4,2048,64]
  f16*  vb  = (f16*)(kb + 2097152);   // [4,4,64,2048] f16 (transposed!)
  bf16* aob = (bf16*)(vb + 2097152);  // [4,2048,1024]

  cast_all<<<10752, 256, 0, stream>>>(x, Wq, Wkv, Wproj, xb, w1b, wpb);
  gemm_qkv<<<dim3(12, 64), 256, 0, stream>>>(xb, w1b, qb, kb, vb);
  attn_alibi<<<dim3(32, 64), 256, 0, stream>>>(qb, kb, vb, aob);
  gemm_proj<<<dim3(8, 64), 256, 0, stream>>>(aob, wpb, bproj, out);
}

// Round 8
// 634.445 us; speedup vs baseline: 1.7345x; 1.7345x over previous
//
#include <hip/hip_runtime.h>
#include <hip/hip_bf16.h>
#include <cstdint>

typedef __bf16 bf16;
typedef bf16 bf16x4 __attribute__((ext_vector_type(4)));
typedef bf16 bf16x8 __attribute__((ext_vector_type(8)));
typedef _Float16 f16;
typedef f16 f16x2 __attribute__((ext_vector_type(2)));
typedef f16 f16x4 __attribute__((ext_vector_type(4)));
typedef f16 f16x8 __attribute__((ext_vector_type(8)));
typedef float f32x4 __attribute__((ext_vector_type(4)));

#define MFMA16(a, b, c) __builtin_amdgcn_mfma_f32_16x16x32_bf16((a), (b), (c), 0, 0, 0)
#define MFMA16HF(a, b, c) __builtin_amdgcn_mfma_f32_16x16x32_f16((a), (b), (c), 0, 0, 0)

// 0.125 * log2(e): folded into Q at the QKV-GEMM epilogue
#define QSCALE 0.18033688011112042f

// async global->LDS DMA, 16B/lane. LDS dest must be wave-uniform base + lane*16.
__device__ inline void async16(const bf16* g, bf16* l) {
  __builtin_amdgcn_global_load_lds(
      (const __attribute__((address_space(1))) void*)g,
      (__attribute__((address_space(3))) void*)l, 16, 0, 0);
}

// ------------------------------------------------------------------
// fused cast fp32 -> bf16 for all four inputs (one launch)
// ------------------------------------------------------------------
__global__ void cast_all(const float* __restrict__ x, const float* __restrict__ wq,
                         const float* __restrict__ wkv, const float* __restrict__ wp,
                         bf16* __restrict__ xb, bf16* __restrict__ w1b,
                         bf16* __restrict__ wpb) {
  const int i = blockIdx.x * blockDim.x + threadIdx.x;
  const float4* src;
  bf16x4* dst;
  int idx;
  if (i < 2097152) {
    src = (const float4*)x; dst = (bf16x4*)xb; idx = i;
  } else if (i < 2359296) {
    src = (const float4*)wq; dst = (bf16x4*)w1b; idx = i - 2097152;
  } else if (i < 2490368) {
    src = (const float4*)wkv; dst = (bf16x4*)(w1b + 1048576); idx = i - 2359296;
  } else {
    src = (const float4*)wp; dst = (bf16x4*)wpb; idx = i - 2490368;
  }
  const float4 v = src[idx];
  bf16x4 o;
  o.x = (bf16)v.x; o.y = (bf16)v.y; o.z = (bf16)v.z; o.w = (bf16)v.w;
  dst[idx] = o;
}

// ------------------------------------------------------------------
// GEMM1: C[m,e] = sum_c x[m,c] * W1[e,c]   (M=8192, N=1536, K=1024)
// Q pre-scaled by QSCALE (bf16), K bf16 [b,kvh,t,d], V f16 [b,kvh,t,d]
// ------------------------------------------------------------------
__global__ __launch_bounds__(256, 2)
void gemm_qkv(const bf16* __restrict__ A, const bf16* __restrict__ B,
              bf16* __restrict__ qb, bf16* __restrict__ kb, f16* __restrict__ vb) {
  constexpr int K = 1024;
  __shared__ bf16 sA[128 * 64];
  __shared__ bf16 sB[128 * 64];
  const int tid = threadIdx.x;
  const int lane = tid & 63, wid = tid >> 6;
  const int col = lane & 15, quad = lane >> 4;
  const int wm = wid >> 1, wn = wid & 1;
  const int m0 = blockIdx.y * 128, n0 = blockIdx.x * 128;
  const int c7 = col & 7;

  f32x4 acc[4][4];
  const f32x4 z = {0.f, 0.f, 0.f, 0.f};
#pragma unroll
  for (int mi = 0; mi < 4; mi++)
#pragma unroll
    for (int ni = 0; ni < 4; ni++) acc[mi][ni] = z;

  for (int k0 = 0; k0 < K; k0 += 64) {
    __syncthreads();
#pragma unroll
    for (int c = 0; c < 4; ++c) {
      const int idx = c * 256 + tid;
      const int row = idx >> 3, kc = idx & 7;
      const int gkc = kc ^ (row & 7);
      async16(&A[(size_t)(m0 + row) * K + k0 + gkc * 8], &sA[idx * 8]);
      async16(&B[(size_t)(n0 + row) * K + k0 + gkc * 8], &sB[idx * 8]);
    }
    __syncthreads();  // vmcnt(0) drain: DMA complete
#pragma unroll
    for (int ks = 0; ks < 2; ++ks) {
      bf16x8 af[4], bfr[4];
#pragma unroll
      for (int i = 0; i < 4; i++)
        af[i] = *(const bf16x8*)&sA[(wm * 64 + i * 16 + col) * 64 +
                                    (((ks * 4 + quad) ^ c7) << 3)];
#pragma unroll
      for (int i = 0; i < 4; i++)
        bfr[i] = *(const bf16x8*)&sB[(wn * 64 + i * 16 + col) * 64 +
                                     (((ks * 4 + quad) ^ c7) << 3)];
#pragma unroll
      for (int mi = 0; mi < 4; mi++)
#pragma unroll
        for (int ni = 0; ni < 4; ni++)
          acc[mi][ni] = MFMA16(af[mi], bfr[ni], acc[mi][ni]);
    }
  }
#pragma unroll
  for (int mi = 0; mi < 4; mi++) {
#pragma unroll
    for (int ni = 0; ni < 4; ni++) {
      const int e = n0 + wn * 64 + ni * 16 + col;
#pragma unroll
      for (int r = 0; r < 4; r++) {
        const int m = m0 + wm * 64 + mi * 16 + quad * 4 + r;
        const int bb = m >> 11, t = m & 2047;
        if (e < 1024) {
          qb[(((size_t)bb * 16 + (e >> 6)) * 2048 + t) * 64 + (e & 63)] =
              (bf16)(acc[mi][ni][r] * QSCALE);
        } else if (e < 1280) {
          const int f = e - 1024;
          kb[(((size_t)bb * 4 + (f >> 6)) * 2048 + t) * 64 + (f & 63)] =
              (bf16)acc[mi][ni][r];
        } else {
          const int f = e - 1280;
          vb[(((size_t)bb * 4 + (f >> 6)) * 2048 + t) * 64 + (f & 63)] =
              (f16)acc[mi][ni][r];
        }
      }
    }
  }
}

// ------------------------------------------------------------------
// GEMM2: out[m,e] = sum_c AO[m,c] * Wproj[e,c] + bias[e]  (fp32 out)
// ------------------------------------------------------------------
__global__ __launch_bounds__(256, 2)
void gemm_proj(const bf16* __restrict__ A, const bf16* __restrict__ B,
               const float* __restrict__ bias, float* __restrict__ out) {
  constexpr int K = 1024;
  __shared__ bf16 sA[128 * 64];
  __shared__ bf16 sB[128 * 64];
  const int tid = threadIdx.x;
  const int lane = tid & 63, wid = tid >> 6;
  const int col = lane & 15, quad = lane >> 4;
  const int wm = wid >> 1, wn = wid & 1;
  const int m0 = blockIdx.y * 128, n0 = blockIdx.x * 128;
  const int c7 = col & 7;

  f32x4 acc[4][4];
  const f32x4 z = {0.f, 0.f, 0.f, 0.f};
#pragma unroll
  for (int mi = 0; mi < 4; mi++)
#pragma unroll
    for (int ni = 0; ni < 4; ni++) acc[mi][ni] = z;

  for (int k0 = 0; k0 < K; k0 += 64) {
    __syncthreads();
#pragma unroll
    for (int c = 0; c < 4; ++c) {
      const int idx = c * 256 + tid;
      const int row = idx >> 3, kc = idx & 7;
      const int gkc = kc ^ (row & 7);
      async16(&A[(size_t)(m0 + row) * K + k0 + gkc * 8], &sA[idx * 8]);
      async16(&B[(size_t)(n0 + row) * K + k0 + gkc * 8], &sB[idx * 8]);
    }
    __syncthreads();
#pragma unroll
    for (int ks = 0; ks < 2; ++ks) {
      bf16x8 af[4], bfr[4];
#pragma unroll
      for (int i = 0; i < 4; i++)
        af[i] = *(const bf16x8*)&sA[(wm * 64 + i * 16 + col) * 64 +
                                    (((ks * 4 + quad) ^ c7) << 3)];
#pragma unroll
      for (int i = 0; i < 4; i++)
        bfr[i] = *(const bf16x8*)&sB[(wn * 64 + i * 16 + col) * 64 +
                                     (((ks * 4 + quad) ^ c7) << 3)];
#pragma unroll
      for (int mi = 0; mi < 4; mi++)
#pragma unroll
        for (int ni = 0; ni < 4; ni++)
          acc[mi][ni] = MFMA16(af[mi], bfr[ni], acc[mi][ni]);
    }
  }
#pragma unroll
  for (int mi = 0; mi < 4; mi++) {
#pragma unroll
    for (int ni = 0; ni < 4; ni++) {
      const int e = n0 + wn * 64 + ni * 16 + col;
      const float be = bias[e];
#pragma unroll
      for (int r = 0; r < 4; r++) {
        const int m = m0 + wm * 64 + mi * 16 + quad * 4 + r;
        out[(size_t)m * 1024 + e] = acc[mi][ni][r] + be;
      }
    }
  }
}

// ------------------------------------------------------------------
// Flash attention v5: block-level kv-split (z=2, 1024 kv each).
// r4/r5 LDS dataflow: K reg-prefetch -> sK (bf16, xor-swizzled),
// V reg-prefetch -> sVt f16 [d][kv] swizzled; P via half-sized
// wave-private sPh (two 32-kv halves); PV = V^T P^T (f16 x32 MFMA,
// output O^T).  Row sums in-lane VALU + 2 end shuffles.
// Partials: O^T f16 + l f32 -> global; combine kernel sums z.
// ------------------------------------------------------------------
__global__ __launch_bounds__(256, 3)
void attn_alibi(const bf16* __restrict__ qb, const bf16* __restrict__ kbp,
                const f16* __restrict__ vbp, f16* __restrict__ op0,
                f16* __restrict__ op1, float* __restrict__ lpart) {
  __shared__ bf16 sK[64 * 64];     // [kv][d], xor-swizzled stride 64
  __shared__ f16 sVt[64 * 72];     // [d][kv], stride 72, kv-block xor-swizzle
  __shared__ f16 sPh[4][64 * 32];  // per wave: [q][32 kv half], xor-swizzled
  const int tid = threadIdx.x;
  const int lane = tid & 63, wid = tid >> 6;
  const int col = lane & 15, quad = lane >> 4;
  const int c7 = col & 7;
  const int bh = blockIdx.y;
  const int b = bh >> 4, h = bh & 15, kvh = h & 3;
  const int qbase = __builtin_amdgcn_readfirstlane(blockIdx.x * 256 + wid * 64);
  const int zb = blockIdx.z;
  const int kvbase = zb * 1024;

  const bf16* qptr = qb + ((size_t)(b * 16 + h) * 2048 + qbase) * 64;
  const bf16* kptr = kbp + ((size_t)((b * 4 + kvh) * 2048 + kvbase)) * 64;
  const f16* vptr = vbp + ((size_t)((b * 4 + kvh) * 2048 + kvbase)) * 64;

  // Q resident as B-operand frags (x32): B[n=q(col)][k=d=ks*32+quad*8+j]
  bf16x8 bq[4][2];
#pragma unroll
  for (int ni = 0; ni < 4; ni++)
#pragma unroll
    for (int ks = 0; ks < 2; ks++)
      bq[ni][ks] = *(const bf16x8*)&qptr[(ni * 16 + col) * 64 + ks * 32 + quad * 8];

  f32x4 OT[4][4];  // O^T[nd][ni]; lane: d=nd*16+quad*4+r, q=ni*16+col
  float lsum[4] = {0.f, 0.f, 0.f, 0.f};
  const f32x4 z = {0.f, 0.f, 0.f, 0.f};
#pragma unroll
  for (int nd = 0; nd < 4; nd++)
#pragma unroll
    for (int ni = 0; ni < 4; ni++) OT[nd][ni] = z;

  const float cb = exp2f(-0.5f * (float)(h + 1)) * QSCALE;  // bias slope, exp2 dom
  const int qoff = quad * 4 - col;

  // staging coords: K rows (tid>>3, +32); V row pair (2*(tid>>3), +1)
  const int rk0 = tid >> 3, rk1 = 32 + rk0, kc = tid & 7;
  const int rv = rk0 * 2;
  const int blkv = rv >> 3, rlv = rv & 7;
  const int kx = (kc ^ (rk0 & 7)) << 3;

  // prefetch chunk 0
  bf16x8 kr0 = *(const bf16x8*)&kptr[(size_t)rk0 * 64 + kc * 8];
  bf16x8 kr1 = *(const bf16x8*)&kptr[(size_t)rk1 * 64 + kc * 8];
  f16x8 vr0 = *(const f16x8*)&vptr[(size_t)rv * 64 + kc * 8];
  f16x8 vr1 = *(const f16x8*)&vptr[(size_t)(rv + 1) * 64 + kc * 8];

  f16* sp = sPh[wid];

  for (int cc = 0; cc < 16; ++cc) {
    const int c0 = kvbase + cc * 64;
    __syncthreads();  // all waves done reading sK/sVt from previous chunk
    *(bf16x8*)&sK[rk0 * 64 + kx] = kr0;
    *(bf16x8*)&sK[rk1 * 64 + kx] = kr1;
#pragma unroll
    for (int j = 0; j < 8; j++) {
      f16x2 pr;
      pr.x = vr0[j];
      pr.y = vr1[j];
      *(f16x2*)&sVt[(kc * 8 + j) * 72 + ((blkv ^ kc) << 3) + rlv] = pr;
    }
    __syncthreads();  // staging visible

    // prefetch next chunk (covered by this chunk's compute)
    {
      const int cof = (cc + 1 < 16) ? (cc + 1) * 64 : 0;
      kr0 = *(const bf16x8*)&kptr[(size_t)(cof + rk0) * 64 + kc * 8];
      kr1 = *(const bf16x8*)&kptr[(size_t)(cof + rk1) * 64 + kc * 8];
      vr0 = *(const f16x8*)&vptr[(size_t)(cof + rv) * 64 + kc * 8];
      vr1 = *(const f16x8*)&vptr[(size_t)(cof + rv + 1) * 64 + kc * 8];
    }

    // two 32-kv halves: QK -> exp -> sPh -> PV
#pragma unroll
    for (int half = 0; half < 2; half++) {
#pragma unroll
      for (int kb2 = 0; kb2 < 2; kb2++) {
        const int kb = half * 2 + kb2;
        // QK for this 16-kv block: S^T rows kv=kb*16+quad*4+r, cols q
        bf16x8 ak[2];
#pragma unroll
        for (int ks = 0; ks < 2; ks++)
          ak[ks] = *(const bf16x8*)&sK[(kb * 16 + col) * 64 +
                                       (((ks * 4 + quad) ^ c7) << 3)];
        f32x4 S[4];
#pragma unroll
        for (int ni = 0; ni < 4; ni++) S[ni] = z;
#pragma unroll
        for (int ks = 0; ks < 2; ks++)
#pragma unroll
          for (int ni = 0; ni < 4; ni++)
            S[ni] = MFMA16(ak[ks], bq[ni][ks], S[ni]);

        // bias + exp2 (fixed max M=0), in-lane row-sum partials, pack f16
#pragma unroll
        for (int ni = 0; ni < 4; ni++) {
          const int U = c0 + kb * 16 - qbase - ni * 16;  // wave-uniform
          f32x4 p;
          if (U <= -15) {
            const float bb = cb * (float)(U + qoff);
#pragma unroll
            for (int r = 0; r < 4; r++)
              p[r] = __builtin_amdgcn_exp2f(S[ni][r] + (bb + cb * (float)r));
          } else if (U >= 16) {
#pragma unroll
            for (int r = 0; r < 4; r++)
              p[r] = __builtin_amdgcn_exp2f(S[ni][r]);
          } else {
            const float relf = (float)(U + qoff);
#pragma unroll
            for (int r = 0; r < 4; r++) {
              const float rr = relf + (float)r;
              const float bb = (rr <= 0.f) ? cb * rr : 0.f;
              p[r] = __builtin_amdgcn_exp2f(S[ni][r] + bb);
            }
          }
          lsum[ni] += (p[0] + p[1]) + (p[2] + p[3]);
          f16x4 w;
#pragma unroll
          for (int r = 0; r < 4; r++) w[r] = (f16)p[r];
          // unit u = kb2*4+quad within half, xor-swizzled by col&7
          *(f16x4*)&sp[((ni * 16 + col) << 5) + (((kb2 * 4 + quad) ^ c7) << 2)] = w;
        }
      }

      // PV: A = V^T frags (sVt), B = P^T frags (sPh)  [k = 32 kv of half]
      f16x8 av[4], pb[4];
#pragma unroll
      for (int nd = 0; nd < 4; nd++) {
        const int d = nd * 16 + col;
        av[nd] = *(const f16x8*)&sVt[d * 72 + (((half * 4 + quad) ^ (d >> 3)) << 3)];
      }
#pragma unroll
      for (int ni = 0; ni < 4; ni++) {
        const int rowo = (ni * 16 + col) << 5;
        *(f16x4*)&pb[ni] = *(const f16x4*)&sp[rowo + (((2 * quad) ^ c7) << 2)];
        *((f16x4*)&pb[ni] + 1) = *(const f16x4*)&sp[rowo + (((2 * quad + 1) ^ c7) << 2)];
      }
#pragma unroll
      for (int ni = 0; ni < 4; ni++)
#pragma unroll
        for (int nd = 0; nd < 4; nd++)
          OT[nd][ni] = MFMA16HF(av[nd], pb[ni], OT[nd][ni]);
    }
  }

  // finish l: reduce over quad groups (kv strides) — 2 shuffles
#pragma unroll
  for (int ni = 0; ni < 4; ni++) {
    float l = lsum[ni];
    l += __shfl_xor(l, 16);
    l += __shfl_xor(l, 32);
    lsum[ni] = l;
  }

  // partial epilogue: O^T f16 -> op[z], l f32 -> lpart[z]
  f16* op = zb ? op1 : op0;
#pragma unroll
  for (int ni = 0; ni < 4; ni++) {
    const int t = qbase + ni * 16 + col;
    const size_t rowb = ((size_t)b * 2048 + t) * 1024 + h * 64;
#pragma unroll
    for (int nd = 0; nd < 4; nd++) {
      f16x4 w;
#pragma unroll
      for (int r = 0; r < 4; r++) w[r] = (f16)OT[nd][ni][r];
      *(f16x4*)&op[rowb + nd * 16 + quad * 4] = w;
    }
    if (quad == 0)
      lpart[zb * 131072 + (b * 16 + h) * 2048 + t] = lsum[ni];
  }
}

// ------------------------------------------------------------------
// combine: aob[row, e] = (op0 + op1) / (l0 + l1)   (bf16 out)
// ------------------------------------------------------------------
__global__ void combine(const f16* __restrict__ op0, const f16* __restrict__ op1,
                        const float* __restrict__ lpart, bf16* __restrict__ aob) {
  const int i = blockIdx.x * 256 + threadIdx.x;  // 1,048,576 threads
  const size_t base = (size_t)i * 8;
  const int row = (int)(base >> 10);  // b*2048 + t
  const int e = (int)(base & 1023);
  const int b = row >> 11, t = row & 2047;
  const int h = e >> 6;
  const int li = (b * 16 + h) * 2048 + t;
  const float inv = 1.0f / (lpart[li] + lpart[131072 + li]);
  const f16x8 a = *(const f16x8*)&op0[base];
  const f16x8 c = *(const f16x8*)&op1[base];
  bf16x8 o;
#pragma unroll
  for (int j = 0; j < 8; j++) o[j] = (bf16)(((float)a[j] + (float)c[j]) * inv);
  *(bf16x8*)&aob[base] = o;
}

// ------------------------------------------------------------------
extern "C" void kernel_launch(void* const* d_in, const int* in_sizes, int n_in,
                              void* d_out, int out_size, void* d_ws, size_t ws_size,
                              hipStream_t stream) {
  const float* x     = (const float*)d_in[0];
  const float* Wq    = (const float*)d_in[1];
  const float* Wkv   = (const float*)d_in[2];
  const float* Wproj = (const float*)d_in[3];
  const float* bproj = (const float*)d_in[4];
  float* out = (float*)d_out;

  // workspace (2-byte element offsets; 64 MB total, same as prior rounds)
  bf16* xb   = (bf16*)d_ws;            // 8,388,608  (x bf16; later opart0 f16)
  bf16* w1b  = xb + 8388608;           // 1,572,864  (Wq|Wkv; later lpart f32)
  bf16* wpb  = w1b + 1572864;          // 1,048,576
  bf16* qb   = wpb + 1048576;          // 8,388,608  (Q; later aob bf16)
  bf16* kb   = qb + 8388608;           // 2,097,152
  f16*  vb   = (f16*)(kb + 2097152);   // 2,097,152 (f16)
  f16*  op1  = (f16*)(vb + 2097152);   // 8,388,608  (opart z=1)

  f16*   op0   = (f16*)xb;     // aliases xb (dead after gemm_qkv)
  float* lpart = (float*)w1b;  // aliases w1b (dead after gemm_qkv)
  bf16*  aob   = qb;           // aliases qb (dead after attn)

  cast_all<<<10752, 256, 0, stream>>>(x, Wq, Wkv, Wproj, xb, w1b, wpb);
  gemm_qkv<<<dim3(12, 64), 256, 0, stream>>>(xb, w1b, qb, kb, vb);
  attn_alibi<<<dim3(8, 64, 2), 256, 0, stream>>>(qb, kb, vb, op0, op1, lpart);
  combine<<<4096, 256, 0, stream>>>(op0, op1, lpart, aob);
  gemm_proj<<<dim3(8, 64), 256, 0, stream>>>(aob, wpb, bproj, out);
}

// Round 9
// 253.981 us; speedup vs baseline: 4.3328x; 2.4980x over previous
//
#include <hip/hip_runtime.h>
#include <hip/hip_bf16.h>
#include <cstdint>

typedef __bf16 bf16;
typedef bf16 bf16x2 __attribute__((ext_vector_type(2)));
typedef bf16 bf16x4 __attribute__((ext_vector_type(4)));
typedef bf16 bf16x8 __attribute__((ext_vector_type(8)));
typedef float f32x4 __attribute__((ext_vector_type(4)));

#define MFMA16(a, b, c) __builtin_amdgcn_mfma_f32_16x16x32_bf16((a), (b), (c), 0, 0, 0)

// 0.125 * log2(e): folded into Q at the QKV-GEMM epilogue
#define QSCALE 0.18033688011112042f

// async global->LDS DMA, 16B/lane. LDS dest must be wave-uniform base + lane*16.
__device__ inline void async16(const bf16* g, bf16* l) {
  __builtin_amdgcn_global_load_lds(
      (const __attribute__((address_space(1))) void*)g,
      (__attribute__((address_space(3))) void*)l, 16, 0, 0);
}

// ------------------------------------------------------------------
// fused cast fp32 -> bf16 for all four inputs (one launch)
// ------------------------------------------------------------------
__global__ void cast_all(const float* __restrict__ x, const float* __restrict__ wq,
                         const float* __restrict__ wkv, const float* __restrict__ wp,
                         bf16* __restrict__ xb, bf16* __restrict__ w1b,
                         bf16* __restrict__ wpb) {
  const int i = blockIdx.x * blockDim.x + threadIdx.x;
  const float4* src;
  bf16x4* dst;
  int idx;
  if (i < 2097152) {
    src = (const float4*)x; dst = (bf16x4*)xb; idx = i;
  } else if (i < 2359296) {
    src = (const float4*)wq; dst = (bf16x4*)w1b; idx = i - 2097152;
  } else if (i < 2490368) {
    src = (const float4*)wkv; dst = (bf16x4*)(w1b + 1048576); idx = i - 2359296;
  } else {
    src = (const float4*)wp; dst = (bf16x4*)wpb; idx = i - 2490368;
  }
  const float4 v = src[idx];
  bf16x4 o;
  o.x = (bf16)v.x; o.y = (bf16)v.y; o.z = (bf16)v.z; o.w = (bf16)v.w;
  dst[idx] = o;
}

// ------------------------------------------------------------------
// GEMM1: C[m,e] = sum_c x[m,c] * W1[e,c]   (M=8192, N=1536, K=1024)
// global_load_lds staging, xor-swizzled unpadded LDS (stride 64).
// Q outputs pre-scaled by QSCALE for the attention exp2 domain.
// ------------------------------------------------------------------
__global__ __launch_bounds__(256, 2)
void gemm_qkv(const bf16* __restrict__ A, const bf16* __restrict__ B,
              bf16* __restrict__ qb, bf16* __restrict__ kb, bf16* __restrict__ vb) {
  constexpr int K = 1024;
  __shared__ bf16 sA[128 * 64];
  __shared__ bf16 sB[128 * 64];
  const int tid = threadIdx.x;
  const int lane = tid & 63, wid = tid >> 6;
  const int col = lane & 15, quad = lane >> 4;
  const int wm = wid >> 1, wn = wid & 1;
  const int m0 = blockIdx.y * 128, n0 = blockIdx.x * 128;
  const int c7 = col & 7;

  f32x4 acc[4][4];
  const f32x4 z = {0.f, 0.f, 0.f, 0.f};
#pragma unroll
  for (int mi = 0; mi < 4; mi++)
#pragma unroll
    for (int ni = 0; ni < 4; ni++) acc[mi][ni] = z;

  for (int k0 = 0; k0 < K; k0 += 64) {
    __syncthreads();
#pragma unroll
    for (int c = 0; c < 4; ++c) {
      const int idx = c * 256 + tid;
      const int row = idx >> 3, kc = idx & 7;
      const int gkc = kc ^ (row & 7);
      async16(&A[(size_t)(m0 + row) * K + k0 + gkc * 8], &sA[idx * 8]);
      async16(&B[(size_t)(n0 + row) * K + k0 + gkc * 8], &sB[idx * 8]);
    }
    __syncthreads();  // vmcnt(0) drain: DMA complete
#pragma unroll
    for (int ks = 0; ks < 2; ++ks) {
      bf16x8 af[4], bfr[4];
#pragma unroll
      for (int i = 0; i < 4; i++)
        af[i] = *(const bf16x8*)&sA[(wm * 64 + i * 16 + col) * 64 +
                                    (((ks * 4 + quad) ^ c7) << 3)];
#pragma unroll
      for (int i = 0; i < 4; i++)
        bfr[i] = *(const bf16x8*)&sB[(wn * 64 + i * 16 + col) * 64 +
                                     (((ks * 4 + quad) ^ c7) << 3)];
#pragma unroll
      for (int mi = 0; mi < 4; mi++)
#pragma unroll
        for (int ni = 0; ni < 4; ni++)
          acc[mi][ni] = MFMA16(af[mi], bfr[ni], acc[mi][ni]);
    }
  }
#pragma unroll
  for (int mi = 0; mi < 4; mi++) {
#pragma unroll
    for (int ni = 0; ni < 4; ni++) {
      const int e = n0 + wn * 64 + ni * 16 + col;
#pragma unroll
      for (int r = 0; r < 4; r++) {
        const int m = m0 + wm * 64 + mi * 16 + quad * 4 + r;
        const int bb = m >> 11, t = m & 2047;
        if (e < 1024) {
          qb[(((size_t)bb * 16 + (e >> 6)) * 2048 + t) * 64 + (e & 63)] =
              (bf16)(acc[mi][ni][r] * QSCALE);
        } else if (e < 1280) {
          const int f = e - 1024;
          kb[(((size_t)bb * 4 + (f >> 6)) * 2048 + t) * 64 + (f & 63)] =
              (bf16)acc[mi][ni][r];
        } else {
          const int f = e - 1280;
          vb[(((size_t)bb * 4 + (f >> 6)) * 2048 + t) * 64 + (f & 63)] =
              (bf16)acc[mi][ni][r];
        }
      }
    }
  }
}

// ------------------------------------------------------------------
// GEMM2: out[m,e] = sum_c AO[m,c] * Wproj[e,c] + bias[e]  (fp32 out)
// ------------------------------------------------------------------
__global__ __launch_bounds__(256, 2)
void gemm_proj(const bf16* __restrict__ A, const bf16* __restrict__ B,
               const float* __restrict__ bias, float* __restrict__ out) {
  constexpr int K = 1024;
  __shared__ bf16 sA[128 * 64];
  __shared__ bf16 sB[128 * 64];
  const int tid = threadIdx.x;
  const int lane = tid & 63, wid = tid >> 6;
  const int col = lane & 15, quad = lane >> 4;
  const int wm = wid >> 1, wn = wid & 1;
  const int m0 = blockIdx.y * 128, n0 = blockIdx.x * 128;
  const int c7 = col & 7;

  f32x4 acc[4][4];
  const f32x4 z = {0.f, 0.f, 0.f, 0.f};
#pragma unroll
  for (int mi = 0; mi < 4; mi++)
#pragma unroll
    for (int ni = 0; ni < 4; ni++) acc[mi][ni] = z;

  for (int k0 = 0; k0 < K; k0 += 64) {
    __syncthreads();
#pragma unroll
    for (int c = 0; c < 4; ++c) {
      const int idx = c * 256 + tid;
      const int row = idx >> 3, kc = idx & 7;
      const int gkc = kc ^ (row & 7);
      async16(&A[(size_t)(m0 + row) * K + k0 + gkc * 8], &sA[idx * 8]);
      async16(&B[(size_t)(n0 + row) * K + k0 + gkc * 8], &sB[idx * 8]);
    }
    __syncthreads();
#pragma unroll
    for (int ks = 0; ks < 2; ++ks) {
      bf16x8 af[4], bfr[4];
#pragma unroll
      for (int i = 0; i < 4; i++)
        af[i] = *(const bf16x8*)&sA[(wm * 64 + i * 16 + col) * 64 +
                                    (((ks * 4 + quad) ^ c7) << 3)];
#pragma unroll
      for (int i = 0; i < 4; i++)
        bfr[i] = *(const bf16x8*)&sB[(wn * 64 + i * 16 + col) * 64 +
                                     (((ks * 4 + quad) ^ c7) << 3)];
#pragma unroll
      for (int mi = 0; mi < 4; mi++)
#pragma unroll
        for (int ni = 0; ni < 4; ni++)
          acc[mi][ni] = MFMA16(af[mi], bfr[ni], acc[mi][ni]);
    }
  }
#pragma unroll
  for (int mi = 0; mi < 4; mi++) {
#pragma unroll
    for (int ni = 0; ni < 4; ni++) {
      const int e = n0 + wn * 64 + ni * 16 + col;
      const float be = bias[e];
#pragma unroll
      for (int r = 0; r < 4; r++) {
        const int m = m0 + wm * 64 + mi * 16 + quad * 4 + r;
        out[(size_t)m * 1024 + e] = acc[mi][ni][r] + be;
      }
    }
  }
}

// ------------------------------------------------------------------
// Flash attention (r4 structure, best measured): ALiBi bias, fixed-max
// softmax, transposed QK dataflow, Q pre-scaled (exp2 domain), row sums
// via all-ones MFMA B-operand, K/V reg-prefetch issued after the 2nd
// barrier.  r9 refinement: exp and PV interleaved at half-chunk
// granularity so PV(ks=0) MFMAs overlap the second exp half's VALU.
// ------------------------------------------------------------------
__global__ __launch_bounds__(256, 2)
void attn_alibi(const bf16* __restrict__ qb, const bf16* __restrict__ kbp,
                const bf16* __restrict__ vbp, bf16* __restrict__ ob) {
  __shared__ bf16 sK[64 * 64];      // [kv][d], xor-swizzled stride 64
  __shared__ bf16 sVt[64 * 72];     // [d][kv], stride 72, kv-block xor-swizzle
  __shared__ bf16 sPt[4][64 * 64];  // per wave: [q][kv], xor-swizzled stride 64
  const int tid = threadIdx.x;
  const int lane = tid & 63, wid = tid >> 6;
  const int col = lane & 15, quad = lane >> 4;
  const int c7 = col & 7;
  const int bh = blockIdx.y;
  const int b = bh >> 4, h = bh & 15, kvh = h & 3;
  const int qbase = __builtin_amdgcn_readfirstlane(blockIdx.x * 256 + wid * 64);

  const bf16* qptr = qb + ((size_t)(b * 16 + h) * 2048 + qbase) * 64;
  const bf16* kptr = kbp + ((size_t)(b * 4 + kvh) * 2048) * 64;
  const bf16* vptr = vbp + ((size_t)(b * 4 + kvh) * 2048) * 64;

  // Q resident as B-operand frags: B[n=q (col)][k=d]
  bf16x8 bq[4][2];
#pragma unroll
  for (int ni = 0; ni < 4; ni++)
#pragma unroll
    for (int ks = 0; ks < 2; ks++)
      bq[ni][ks] = *(const bf16x8*)&qptr[(ni * 16 + col) * 64 + ks * 32 + quad * 8];

  // all-ones B-frag for MFMA row sums
  bf16x8 bones;
#pragma unroll
  for (int j = 0; j < 8; j++) bones[j] = (bf16)1.0f;

  f32x4 O[4][4];  // O[q-tile][d-tile], C-layout rows=q
  f32x4 Osum[4];  // row sums of P per q-tile
  const f32x4 z = {0.f, 0.f, 0.f, 0.f};
#pragma unroll
  for (int mi = 0; mi < 4; mi++) {
    Osum[mi] = z;
#pragma unroll
    for (int nd = 0; nd < 4; nd++) O[mi][nd] = z;
  }

  const float cb = exp2f(-0.5f * (float)(h + 1)) * QSCALE;  // bias slope, exp2 dom
  const int qoff = quad * 4 - col;

  // staging coords: K rows (tid>>3, +32); V row pair (2*(tid>>3), +1)
  const int rk0 = tid >> 3, rk1 = 32 + rk0, kc = tid & 7;
  const int rv = rk0 * 2;
  const int blkv = rv >> 3, rlv = rv & 7;
  const int kx = (kc ^ (rk0 & 7)) << 3;  // rk1&7 == rk0&7

  // prefetch chunk 0
  bf16x8 kr0 = *(const bf16x8*)&kptr[(size_t)rk0 * 64 + kc * 8];
  bf16x8 kr1 = *(const bf16x8*)&kptr[(size_t)rk1 * 64 + kc * 8];
  bf16x8 vr0 = *(const bf16x8*)&vptr[(size_t)rv * 64 + kc * 8];
  bf16x8 vr1 = *(const bf16x8*)&vptr[(size_t)(rv + 1) * 64 + kc * 8];

  bf16* sp = sPt[wid];

  for (int c0 = 0; c0 < 2048; c0 += 64) {
    __syncthreads();  // all waves done reading previous chunk's sK/sVt
    *(bf16x8*)&sK[rk0 * 64 + kx] = kr0;
    *(bf16x8*)&sK[rk1 * 64 + kx] = kr1;
#pragma unroll
    for (int j = 0; j < 8; j++) {
      bf16x2 pr;
      pr.x = vr0[j];
      pr.y = vr1[j];
      *(bf16x2*)&sVt[(kc * 8 + j) * 72 + ((blkv ^ kc) << 3) + rlv] = pr;
    }
    __syncthreads();  // staging visible; nothing in flight to drain

    // issue next chunk's loads — whole compute phase covers their latency
    {
      const int cn = (c0 + 64 < 2048) ? c0 + 64 : 0;
      kr0 = *(const bf16x8*)&kptr[(size_t)(cn + rk0) * 64 + kc * 8];
      kr1 = *(const bf16x8*)&kptr[(size_t)(cn + rk1) * 64 + kc * 8];
      vr0 = *(const bf16x8*)&vptr[(size_t)(cn + rv) * 64 + kc * 8];
      vr1 = *(const bf16x8*)&vptr[(size_t)(cn + rv + 1) * 64 + kc * 8];
    }

    // S^T = K Q^T : rows=kv, cols=q  (Q pre-scaled: S is in exp2 domain)
    f32x4 S[4][4];
#pragma unroll
    for (int mi = 0; mi < 4; mi++)
#pragma unroll
      for (int ni = 0; ni < 4; ni++) S[mi][ni] = z;
#pragma unroll
    for (int ks = 0; ks < 2; ks++) {
      bf16x8 ak[4];
#pragma unroll
      for (int mi = 0; mi < 4; mi++)
        ak[mi] = *(const bf16x8*)&sK[(mi * 16 + col) * 64 +
                                     (((ks * 4 + quad) ^ c7) << 3)];
#pragma unroll
      for (int mi = 0; mi < 4; mi++)
#pragma unroll
        for (int ni = 0; ni < 4; ni++)
          S[mi][ni] = MFMA16(ak[mi], bq[ni][ks], S[mi][ni]);
    }

    // interleaved: exp half (kv blocks 2ks,2ks+1) -> sPt, then PV(ks)
#pragma unroll
    for (int ks = 0; ks < 2; ks++) {
#pragma unroll
      for (int mh = 0; mh < 2; mh++) {
        const int mi = ks * 2 + mh;
#pragma unroll
        for (int ni = 0; ni < 4; ni++) {
          const int U = c0 + mi * 16 - qbase - ni * 16;  // wave-uniform
          f32x4 p;
          if (U <= -15) {
            const float bb = cb * (float)(U + qoff);
#pragma unroll
            for (int r = 0; r < 4; r++)
              p[r] = __builtin_amdgcn_exp2f(S[mi][ni][r] + (bb + cb * (float)r));
          } else if (U >= 16) {
#pragma unroll
            for (int r = 0; r < 4; r++)
              p[r] = __builtin_amdgcn_exp2f(S[mi][ni][r]);
          } else {
            const float relf = (float)(U + qoff);
#pragma unroll
            for (int r = 0; r < 4; r++) {
              const float rr = relf + (float)r;
              const float bb = (rr <= 0.f) ? cb * rr : 0.f;
              p[r] = __builtin_amdgcn_exp2f(S[mi][ni][r] + bb);
            }
          }
          bf16x4 w;
#pragma unroll
          for (int r = 0; r < 4; r++) w[r] = (bf16)p[r];
          *(bf16x4*)&sp[(ni * 16 + col) * 64 +
                        (((2 * mi + (quad >> 1)) ^ c7) << 3) + ((quad & 1) << 2)] = w;
        }
      }

      // PV(ks): reads only kv elements [ks*32, ks*32+32) of sPt — the half
      // just written.  A = P rows, B = V^T rows (sVt swizzled).
      bf16x8 ap[4], bv[4];
#pragma unroll
      for (int mi = 0; mi < 4; mi++)
        ap[mi] = *(const bf16x8*)&sp[(mi * 16 + col) * 64 +
                                     (((ks * 4 + quad) ^ c7) << 3)];
#pragma unroll
      for (int nd = 0; nd < 4; nd++) {
        const int d = nd * 16 + col;
        bv[nd] = *(const bf16x8*)&sVt[d * 72 + (((ks * 4 + quad) ^ (d >> 3)) << 3)];
      }
#pragma unroll
      for (int mi = 0; mi < 4; mi++) {
#pragma unroll
        for (int nd = 0; nd < 4; nd++)
          O[mi][nd] = MFMA16(ap[mi], bv[nd], O[mi][nd]);
        Osum[mi] = MFMA16(ap[mi], bones, Osum[mi]);
      }
    }
  }

  // epilogue: every lane holds its row sum in Osum[mi][r]
#pragma unroll
  for (int mi = 0; mi < 4; mi++) {
#pragma unroll
    for (int r = 0; r < 4; r++) {
      const float inv = 1.0f / Osum[mi][r];
      const int t = qbase + mi * 16 + quad * 4 + r;
#pragma unroll
      for (int nd = 0; nd < 4; nd++) {
        ob[((size_t)b * 2048 + t) * 1024 + h * 64 + nd * 16 + col] =
            (bf16)(O[mi][nd][r] * inv);
      }
    }
  }
}

// ------------------------------------------------------------------
extern "C" void kernel_launch(void* const* d_in, const int* in_sizes, int n_in,
                              void* d_out, int out_size, void* d_ws, size_t ws_size,
                              hipStream_t stream) {
  const float* x     = (const float*)d_in[0];
  const float* Wq    = (const float*)d_in[1];
  const float* Wkv   = (const float*)d_in[2];
  const float* Wproj = (const float*)d_in[3];
  const float* bproj = (const float*)d_in[4];
  float* out = (float*)d_out;

  bf16* xb  = (bf16*)d_ws;            // 8192*1024
  bf16* w1b = xb  + 8388608;          // 1536*1024
  bf16* wpb = w1b + 1572864;          // 1024*1024
  bf16* qb  = wpb + 1048576;          // [4,16,2048,64]
  bf16* kb  = qb  + 8388608;          // [4,4,2048,64]
  bf16* vb  = kb  + 2097152;          // [4,4,2048,64]
  bf16* aob = vb  + 2097152;          // [4,2048,1024]

  cast_all<<<10752, 256, 0, stream>>>(x, Wq, Wkv, Wproj, xb, w1b, wpb);
  gemm_qkv<<<dim3(12, 64), 256, 0, stream>>>(xb, w1b, qb, kb, vb);
  attn_alibi<<<dim3(8, 64), 256, 0, stream>>>(qb, kb, vb, aob);
  gemm_proj<<<dim3(8, 64), 256, 0, stream>>>(aob, wpb, bproj, out);
}